// Round 13
// baseline (386.788 us; speedup 1.0000x reference)
//
#include <hip/hip_runtime.h>

// ---------------------------------------------------------------------------
// GINENet, N=50000, E=800000, D=128.
// Round 29:
//  * agg_csr launch_bounds (256,4) -> (256,8): VGPR 36 fits the 64/wave
//    budget at 8 waves/EU; doubles resident waves to hide gather latency.
//  * bkt_scan fused into scatter_bkt2 (decoupled-lookback style): block 0
//    scans bcnt->bstart in LDS while other blocks histogram; device-scope
//    atomic flag + threadfence hand-off. All 196 blocks co-resident -> no
//    deadlock. Removes one kernel + boundary.
// Rest identical to r28 (338.7us).
// ---------------------------------------------------------------------------

typedef unsigned short u16;
typedef unsigned int u32;

using bfrag = __attribute__((ext_vector_type(8))) short;  // 8 bf16
using ffrag = __attribute__((ext_vector_type(4))) float;  // 4 fp32 acc

__device__ __forceinline__ u16 f2b(float f) {
    u32 u = __float_as_uint(f);
    return (u16)((u + 0x7FFFu + ((u >> 16) & 1u)) >> 16);   // RNE
}
__device__ __forceinline__ float b2f(u16 h) {
    return __uint_as_float(((u32)h) << 16);
}
__device__ __forceinline__ float b2f_lo(u32 g) { return __uint_as_float(g << 16); }
__device__ __forceinline__ float b2f_hi(u32 g) { return __uint_as_float(g & 0xffff0000u); }

#define BN_EPS 1e-5f
#define BKT_SHIFT 6
#define BKT_NODES 64
#define NBKT_MAX 1024
#define SC_CHUNK 4096
#define SC_THREADS 1024
#define HCHUNK 8192

// ============ weight fold (+BN from raw stats) -> FRAGMENT-MAJOR ============
__device__ __forceinline__
void fold_row(const float* __restrict__ W, const float* __restrict__ bias,
              const float* __restrict__ stA, const float* __restrict__ gA,
              const float* __restrict__ btA, int DA,
              const float* __restrict__ stB, const float* __restrict__ gB,
              const float* __restrict__ btB, int DB,
              u16* __restrict__ WbSw, float* __restrict__ biasp,
              int DOUT, float inv_n, int o, int lane) {
    int DIN = DA + DB;
    int NKT = DIN >> 5;
    int cf = o >> 4, mrow = o & 15;
    if (o >= DOUT) {                    // pad row: zeros
        for (int k = lane; k < DIN; k += 64) {
            int kt = k >> 5, kg = (k >> 3) & 3, e = k & 7;
            WbSw[(((cf * NKT + kt) << 6) + (kg << 4) + mrow) * 8 + e] = 0;
        }
        if (lane == 0) biasp[o] = 0.f;
        return;
    }
    float part = 0.f;
    for (int k = lane; k < DIN; k += 64) {
        float w = W[o * DIN + k];
        float sc = 1.f, sh = 0.f;
        if (k < DA) {
            if (stA) {
                float mu = stA[k] * inv_n;
                float var = stA[DA + k] * inv_n - mu * mu;
                sc = gA[k] * rsqrtf(var + BN_EPS);
                sh = fmaf(-mu, sc, btA[k]);
            }
        } else {
            int kb = k - DA;
            if (stB) {
                float mu = stB[kb] * inv_n;
                float var = stB[DB + kb] * inv_n - mu * mu;
                sc = gB[kb] * rsqrtf(var + BN_EPS);
                sh = fmaf(-mu, sc, btB[kb]);
            }
        }
        int kt = k >> 5, kg = (k >> 3) & 3, e = k & 7;
        WbSw[(((cf * NKT + kt) << 6) + (kg << 4) + mrow) * 8 + e] = f2b(w * sc);
        part += w * sh;
    }
    for (int off = 32; off; off >>= 1) part += __shfl_down(part, off);
    if (lane == 0) biasp[o] = bias[o] + part;
}

__global__ __launch_bounds__(64)
void fold_w(const float* __restrict__ W, const float* __restrict__ bias,
            const float* __restrict__ stA, const float* __restrict__ gA,
            const float* __restrict__ btA, int DA,
            const float* __restrict__ stB, const float* __restrict__ gB,
            const float* __restrict__ btB, int DB,
            u16* __restrict__ WbSw, float* __restrict__ biasp, int DOUT, float inv_n) {
    fold_row(W, bias, stA, gA, btA, DA, stB, gB, btB, DB, WbSw, biasp, DOUT,
             inv_n, blockIdx.x, threadIdx.x);
}

// ===== fused init: bucket histogram + x->bf16 conversion + static folds =====
__global__ __launch_bounds__(256)
void conv_fold_histo(const int* __restrict__ ei, int E, int nh, int nbkt,
                     const float4* __restrict__ src, uint2* __restrict__ dst, int n4,
                     const float* __restrict__ w1, const float* __restrict__ b1,
                     const float* __restrict__ w2, const float* __restrict__ b2,
                     u16* __restrict__ Wb1, u16* __restrict__ Wb2,
                     float* __restrict__ biasp, int2* __restrict__ padEa,
                     int* __restrict__ bcnt) {
    __shared__ int histL[NBKT_MAX];
    int bx = blockIdx.x;
    const int tid = threadIdx.x;
    if (bx < nh) {
        for (int i = tid; i < nbkt; i += 256) histL[i] = 0;
        __syncthreads();
        int j0 = bx * HCHUNK, j1 = min(E, j0 + HCHUNK);
        for (int j = j0 + tid; j < j1; j += 256)
            atomicAdd(&histL[ei[E + j] >> BKT_SHIFT], 1);
        __syncthreads();
        for (int i = tid; i < nbkt; i += 256) {
            int c = histL[i];
            if (c) atomicAdd(&bcnt[i], c);
        }
        return;
    }
    bx -= nh;
    if (bx < 48) {
        int o = bx * 4 + (tid >> 6);
        int lane = tid & 63;
        if (o < 128)
            fold_row(w1, b1, nullptr, nullptr, nullptr, 128, nullptr, nullptr, nullptr, 0,
                     Wb1, biasp + 0, 128, 0.f, o, lane);
        else if (o < 192)
            fold_row(w2, b2, nullptr, nullptr, nullptr, 128, nullptr, nullptr, nullptr, 0,
                     Wb2, biasp + 128, 64, 0.f, o - 128, lane);
        return;
    }
    if (bx == 48) {
        if (tid < 64) padEa[E + tid] = make_int2(0, 0);
        return;
    }
    int i = (bx - 49) * 256 + tid;
    if (i < n4) {
        float4 v = src[i];
        uint2 o;
        o.x = (u32)f2b(v.x) | ((u32)f2b(v.y) << 16);
        o.y = (u32)f2b(v.z) | ((u32)f2b(v.w) << 16);
        dst[i] = o;
    }
}

// ==== scatter (1024-thread blocks) with FUSED bucket scan in block 0 ========
// Block 0 scans bcnt -> bstart (Hillis-Steele in LDS) while other blocks run
// their LDS histogram; hand-off via device-scope atomic flag + threadfence.
// All blocks (196 x 16 waves) are co-resident -> spin cannot deadlock.
__global__ __launch_bounds__(SC_THREADS)
void scatter_bkt2(const int* __restrict__ ei, const float* __restrict__ ea,
                  const int* __restrict__ bcnt, int* __restrict__ bstart,
                  int* __restrict__ bfill, int* __restrict__ flag,
                  int2* __restrict__ bedges, int E, int nbkt) {
    __shared__ int cntL[NBKT_MAX];
    __shared__ int baseL[NBKT_MAX];
    const int tid = threadIdx.x;
    const int e0 = blockIdx.x * SC_CHUNK;
    const int e1 = min(E, e0 + SC_CHUNK);
    for (int i = tid; i < nbkt; i += SC_THREADS) cntL[i] = 0;
    __syncthreads();
    for (int j = e0 + tid; j < e1; j += SC_THREADS)
        atomicAdd(&cntL[ei[E + j] >> BKT_SHIFT], 1);

    if (blockIdx.x == 0) {
        // ---- scan bcnt -> bstart (uses baseL as scratch; phase 3 reuses it)
        int v = (tid < nbkt) ? bcnt[tid] : 0;
        baseL[tid] = v;
        __syncthreads();
        for (int off = 1; off < SC_THREADS; off <<= 1) {
            int x = (tid >= off) ? baseL[tid - off] : 0;
            __syncthreads();
            baseL[tid] += x;
            __syncthreads();
        }
        if (tid < nbkt) bstart[tid] = baseL[tid] - v;   // exclusive
        if (tid == 0) bstart[nbkt] = baseL[nbkt - 1];   // total
        __threadfence();
        __syncthreads();
        if (tid == 0) atomicExch(flag, 1);
    } else {
        __syncthreads();
        if (tid == 0) {
            while (atomicAdd(flag, 0) == 0) { }
        }
        __syncthreads();
        __threadfence();
    }
    __syncthreads();

    for (int i = tid; i < nbkt; i += SC_THREADS) {
        int c = cntL[i];
        baseL[i] = c ? (bstart[i] + atomicAdd(&bfill[i], c)) : 0;
        cntL[i] = 0;   // reuse as cursor
    }
    __syncthreads();
    for (int j = e0 + tid; j < e1; j += SC_THREADS) {
        int src = ei[j];
        int dst = ei[E + j];
        int b = dst >> BKT_SHIFT;
        int pos = baseL[b] + atomicAdd(&cntL[b], 1);
        bedges[pos] = make_int2(src | ((dst & (BKT_NODES - 1)) << 20),
                                __float_as_int(ea[j]));
    }
}

// Bucket-local compaction + per-node CSR metadata.
__global__ __launch_bounds__(256)
void compact_bkt(const int2* __restrict__ bedges, const int* __restrict__ bstart,
                 int2* __restrict__ srcEa, int* __restrict__ startA,
                 int* __restrict__ cnt, int n) {
    __shared__ int cntL[BKT_NODES];
    __shared__ int baseS[BKT_NODES];
    __shared__ int fillL[BKT_NODES];
    const int b = blockIdx.x;
    const int v0 = b << BKT_SHIFT;
    const int e0 = bstart[b];
    const int e1 = bstart[b + 1];
    const int tid = threadIdx.x;
    if (tid < BKT_NODES) { cntL[tid] = 0; fillL[tid] = 0; }
    __syncthreads();
    for (int j = e0 + tid; j < e1; j += 256)
        atomicAdd(&cntL[(bedges[j].x >> 20) & (BKT_NODES - 1)], 1);
    __syncthreads();
    if (tid < 64) {
        int c = cntL[tid];
        int s = c;                       // inclusive scan over the wave
#pragma unroll
        for (int d = 1; d < 64; d <<= 1) {
            int y = __shfl_up(s, d);
            if (tid >= d) s += y;
        }
        int gstart = e0 + s - c;         // exclusive
        baseS[tid] = gstart;
        int v = v0 + tid;
        if (v < n) { startA[v] = gstart; cnt[v] = c; }
    }
    __syncthreads();
    for (int j = e0 + tid; j < e1; j += 256) {
        int2 p = bedges[j];
        int dl = (p.x >> 20) & (BKT_NODES - 1);
        int pos = baseS[dl] + atomicAdd(&fillL[dl], 1);
        srcEa[pos] = make_int2(p.x & 0xFFFFF, p.y);
    }
}

// =================== gather-side GINE aggregation ===========================
// r23 structure; launch_bounds (256,8) for 32 resident waves/CU (VGPR 36 fits
// the 64/wave budget) -- more TLP for the L3/remote-L2 gather latency.
template <bool BN>
__global__ __launch_bounds__(256, 8)
void agg_csr(const u32* __restrict__ x2, const float* __restrict__ ew,
             const float* __restrict__ eb, const int2* __restrict__ srcEa,
             const int* __restrict__ start, const int* __restrict__ cnt,
             const float* __restrict__ stats, const float* __restrict__ g,
             const float* __restrict__ bt, u32* __restrict__ agg2, int n, float inv_n) {
    int v = blockIdx.x * 4 + (threadIdx.x >> 6);
    if (v >= n) return;
    const int lane = threadIdx.x & 63;
    const int s0 = __builtin_amdgcn_readfirstlane(start[v]);
    const int deg = __builtin_amdgcn_readfirstlane(cnt[v]);

    // hoisted independent loads
    u32 gs = x2[(u32)v * 64u + (u32)lane];
    int2 p[8], pn[8];
#pragma unroll
    for (int t = 0; t < 8; ++t) p[t] = srcEa[s0 + t];   // pad makes this safe

    float w0 = ew[2 * lane], w1 = ew[2 * lane + 1];
    float b0 = eb[2 * lane], b1 = eb[2 * lane + 1];
    float sc0 = 1.f, sh0 = 0.f, sc1 = 1.f, sh1 = 0.f;
    if (BN) {
        float mu0 = stats[2 * lane] * inv_n;
        float va0 = stats[128 + 2 * lane] * inv_n - mu0 * mu0;
        sc0 = g[2 * lane] * rsqrtf(va0 + BN_EPS);
        sh0 = fmaf(-mu0, sc0, bt[2 * lane]);
        float mu1 = stats[2 * lane + 1] * inv_n;
        float va1 = stats[129 + 2 * lane] * inv_n - mu1 * mu1;
        sc1 = g[2 * lane + 1] * rsqrtf(va1 + BN_EPS);
        sh1 = fmaf(-mu1, sc1, bt[2 * lane + 1]);
    }
    const float bs0 = BN ? (b0 + sh0) : b0;   // fold BN shift into edge bias
    const float bs1 = BN ? (b1 + sh1) : b1;

    float a0 = 0.f, a1 = 0.f;
    for (int j = 0; j < deg; j += 8) {
        // issue this round's row gathers (saddr form: uniform row base + lane)
        u32 gg[8];
#pragma unroll
        for (int t = 0; t < 8; ++t) {
            u32 row = (u32)__builtin_amdgcn_readfirstlane(p[t].x);
            gg[t] = x2[row * 64u + (u32)lane];
        }
        // prefetch next round's edge records (s_load, overlaps gathers)
        if (j + 8 < deg) {
#pragma unroll
            for (int t = 0; t < 8; ++t) pn[t] = srcEa[s0 + j + 8 + t];
        }
#pragma unroll
        for (int t = 0; t < 8; ++t) {
            float mf = (j + t < deg) ? 1.f : 0.f;       // uniform -> s_cselect
            float eav = __int_as_float(p[t].y);
            float t0 = fmaf(eav, w0, bs0);
            float t1 = fmaf(eav, w1, bs1);
            float m0 = BN ? fmaxf(fmaf(b2f_lo(gg[t]), sc0, t0), 0.f)
                          : fmaxf(b2f_lo(gg[t]) + t0, 0.f);
            float m1 = BN ? fmaxf(fmaf(b2f_hi(gg[t]), sc1, t1), 0.f)
                          : fmaxf(b2f_hi(gg[t]) + t1, 0.f);
            a0 = fmaf(m0, mf, a0);
            a1 = fmaf(m1, mf, a1);
        }
#pragma unroll
        for (int t = 0; t < 8; ++t) p[t] = pn[t];
    }

    float r0 = (BN ? fmaf(b2f_lo(gs), sc0, sh0) : b2f_lo(gs)) + a0;
    float r1 = (BN ? fmaf(b2f_hi(gs), sc1, sh1) : b2f_hi(gs)) + a1;
    agg2[(u32)v * 64u + (u32)lane] = (u32)f2b(r0) | ((u32)f2b(r1) << 16);
}

// ======================= MFMA matmul + relu + stats =========================
template <int DIN0, int DIN1, int DOUTP, int DOUT>
__global__ __launch_bounds__(256)
void mm_mfma(const u16* __restrict__ in0, const u16* __restrict__ in1,
             const u16* __restrict__ WbSw, const float* __restrict__ biasp,
             u16* __restrict__ out, float* __restrict__ stats, int n) {
    constexpr int DIN = DIN0 + DIN1;
    constexpr int BM = 128;
    constexpr int NH = 2;
    constexpr int NCF = DOUTP / 16;
    constexpr int NKT = DIN / 32;
    __shared__ float cs[2 * DOUTP];
    const int tid = threadIdx.x;
    const int row0 = blockIdx.x * BM;
    const int wv = tid >> 6;
    const int lane = tid & 63;
    const int mrow = lane & 15;
    const int kg = lane >> 4;

    ffrag acc[NH][NCF];
#pragma unroll
    for (int h = 0; h < NH; ++h)
#pragma unroll
        for (int cf = 0; cf < NCF; ++cf) acc[h][cf] = (ffrag){0.f, 0.f, 0.f, 0.f};

    const int r0w = row0 + wv * 16 + mrow;   // this lane's base row
#pragma unroll
    for (int kt = 0; kt < NKT; ++kt) {
        const int gk = kt * 32 + kg * 8;
        bfrag a[NH];
#pragma unroll
        for (int h = 0; h < NH; ++h) {
            long gr = r0w + h * 64;
            const u16* src = (DIN1 == 0 || gk < DIN0)
                                 ? (in0 + gr * DIN0 + gk)
                                 : (in1 + gr * DIN1 + (gk - DIN0));
            a[h] = *(const bfrag*)src;
        }
#pragma unroll
        for (int cf = 0; cf < NCF; ++cf) {
            bfrag bb = *(const bfrag*)(WbSw + (((long)(cf * NKT + kt) << 6) + lane) * 8);
#pragma unroll
            for (int h = 0; h < NH; ++h)
                acc[h][cf] = __builtin_amdgcn_mfma_f32_16x16x32_bf16(a[h], bb, acc[h][cf], 0, 0, 0);
        }
    }

    // ---- epilogue: bias + relu + bf16 store + column stats
    for (int i = tid; i < 2 * DOUTP; i += 256) cs[i] = 0.f;
    __syncthreads();

    const int col = lane & 15;
#pragma unroll
    for (int cf = 0; cf < NCF; ++cf) {
        int c = cf * 16 + col;
        if (DOUTP != DOUT && c >= DOUT) continue;
        float bv = biasp[c];
        float bsum = 0.f, bss = 0.f;
#pragma unroll
        for (int h = 0; h < NH; ++h) {
#pragma unroll
            for (int r = 0; r < 4; ++r) {
                int gr = row0 + h * 64 + wv * 16 + kg * 4 + r;
                if (gr < n) {
                    float v = fmaxf(acc[h][cf][r] + bv, 0.f);
                    out[(long)gr * DOUT + c] = f2b(v);
                    bsum += v;
                    bss += v * v;
                }
            }
        }
        atomicAdd(&cs[c], bsum);
        atomicAdd(&cs[DOUT + c], bss);
    }
    __syncthreads();
    for (int i = tid; i < 2 * DOUT; i += 256) atomicAdd(&stats[i], cs[i]);
}

// ===================== final BN (raw stats -> output) =======================
__global__ void bn_apply_out(const u16* __restrict__ t, const float* __restrict__ stats,
                             const float* __restrict__ g, const float* __restrict__ beta,
                             float* __restrict__ out, int total, float inv_n) {
    int i = blockIdx.x * blockDim.x + threadIdx.x;
    if (i < total) {
        int c = i & 7;
        float mu = stats[c] * inv_n;
        float var = stats[8 + c] * inv_n - mu * mu;
        float sc = g[c] * rsqrtf(var + BN_EPS);
        out[i] = fmaf(b2f(t[i]) - mu, sc, beta[c]);
    }
}

// ============================ driver ========================================
extern "C" void kernel_launch(void* const* d_in, const int* in_sizes, int n_in,
                              void* d_out, int out_size, void* d_ws, size_t ws_size,
                              hipStream_t stream) {
    const float* x    = (const float*)d_in[0];
    const int*   ei   = (const int*)d_in[1];
    const float* ea   = (const float*)d_in[2];
    const float* elw  = (const float*)d_in[3];
    const float* elb  = (const float*)d_in[4];
    const float* c1w  = (const float*)d_in[5];
    const float* c1b  = (const float*)d_in[6];
    const float* c1g  = (const float*)d_in[7];
    const float* c1bt = (const float*)d_in[8];
    const float* c2w  = (const float*)d_in[9];
    const float* c2b  = (const float*)d_in[10];
    const float* c2g  = (const float*)d_in[11];
    const float* c2bt = (const float*)d_in[12];
    const float* l1w  = (const float*)d_in[13];
    const float* l1b  = (const float*)d_in[14];
    const float* l1g  = (const float*)d_in[15];
    const float* l1bt = (const float*)d_in[16];
    const float* m1w  = (const float*)d_in[17];
    const float* m1b  = (const float*)d_in[18];
    const float* m1g  = (const float*)d_in[19];
    const float* m1bt = (const float*)d_in[20];
    const float* m2w  = (const float*)d_in[21];
    const float* m2b  = (const float*)d_in[22];
    const float* m2g  = (const float*)d_in[23];
    const float* m2bt = (const float*)d_in[24];

    const int n = in_sizes[0] / 128;   // 50000
    const int E = in_sizes[2];         // 800000
    const float inv_n = 1.0f / (float)n;
    const int nbkt = (n + BKT_NODES - 1) / BKT_NODES;
    const size_t np = (size_t)((n + 127) & ~127);   // padded rows for mm tiles

    char* wp = (char*)d_ws;
    auto alloc = [&](size_t bytes) { char* p = wp; wp += (bytes + 31) & ~(size_t)31; return p; };

    float* stats  = (float*)alloc(1280 * 4);         // 5 layers x [sum|sumsq]
    float* biasp  = (float*)alloc(5 * 128 * 4);
    int*   bcnt   = (int*)alloc(NBKT_MAX * 4);       // bucket counts
    int*   bfill  = (int*)alloc(NBKT_MAX * 4);       // contiguous after bcnt
    int*   flag   = (int*)alloc(32);                 // contiguous after bfill
    int*   bstart = (int*)alloc((NBKT_MAX + 1) * 4); // bucket starts (scan out)
    int*   cnt    = (int*)alloc((size_t)n * 4);      // per-node degree (stored)
    int*   startA = (int*)alloc((size_t)n * 4);      // per-node CSR start
    int2*  bedges = (int2*)alloc((size_t)E * 8);
    int2*  srcEa  = (int2*)alloc((size_t)(E + 64) * 8);   // +64 zero pad rows
    u16*   xb     = (u16*)alloc(np * 128 * 2);
    u16*   Ab     = (u16*)alloc(np * 128 * 2);
    u16*   T1     = (u16*)alloc(np * 128 * 2);
    u16*   T2     = (u16*)alloc(np * 64 * 2);
    u16*   T3     = (u16*)alloc(np * 96 * 2);
    u16*   T4     = (u16*)alloc(np * 96 * 2);
    u16*   T5     = (u16*)alloc(np * 8 * 2);
    u16*   Wb1    = (u16*)alloc(128 * 128 * 2);
    u16*   Wb2    = (u16*)alloc(64 * 128 * 2);
    u16*   Wb3    = (u16*)alloc(96 * 192 * 2);
    u16*   Wb4    = (u16*)alloc(96 * 96 * 2);
    u16*   Wb5    = (u16*)alloc(16 * 96 * 2);

    hipMemsetAsync(stats, 0, 1280 * 4, stream);
    hipMemsetAsync(bcnt, 0, NBKT_MAX * 2 * 4 + 32, stream);   // bcnt + bfill + flag

    const int ag_grid = (n + 3) / 4;
    const int mm_grid = (n + 127) / 128;
    const int sc_grid = (E + SC_CHUNK - 1) / SC_CHUNK;
    const int nh = (E + HCHUNK - 1) / HCHUNK;
    const int ncv = (n * 32 + 255) / 256;

    // ---- fused init: bucket histo + folds + pad + x conversion
    conv_fold_histo<<<nh + 49 + ncv, 256, 0, stream>>>(
        ei, E, nh, nbkt, (const float4*)x, (uint2*)xb, n * 32,
        c1w, c1b, c2w, c2b, Wb1, Wb2, biasp, srcEa, bcnt);
    scatter_bkt2<<<sc_grid, SC_THREADS, 0, stream>>>(ei, ea, bcnt, bstart, bfill, flag,
                                                     bedges, E, nbkt);
    compact_bkt<<<nbkt, 256, 0, stream>>>(bedges, bstart, srcEa, startA, cnt, n);

    // ---- conv1: agg(x) -> mm1 -> T1 (pre-BN), stats0
    agg_csr<false><<<ag_grid, 256, 0, stream>>>((const u32*)xb, elw, elb, srcEa, startA, cnt,
                                                nullptr, nullptr, nullptr, (u32*)Ab, n, inv_n);
    mm_mfma<128, 0, 128, 128><<<mm_grid, 256, 0, stream>>>(
        Ab, nullptr, Wb1, biasp + 0, T1, stats + 0, n);

    // ---- conv2: agg(BN(T1) inline) -> mm2 -> T2 (pre-BN), stats1
    agg_csr<true><<<ag_grid, 256, 0, stream>>>((const u32*)T1, elw, elb, srcEa, startA, cnt,
                                               stats + 0, c1g, c1bt, (u32*)Ab, n, inv_n);
    mm_mfma<128, 0, 64, 64><<<mm_grid, 256, 0, stream>>>(
        Ab, nullptr, Wb2, biasp + 128, T2, stats + 256, n);

    // ---- lin1: fold W3 from stats0+stats1, mm on raw [T1|T2]
    fold_w<<<96, 64, 0, stream>>>(l1w, l1b, stats + 0, c1g, c1bt, 128,
                                  stats + 256, c2g, c2bt, 64, Wb3, biasp + 256, 96, inv_n);
    mm_mfma<128, 64, 96, 96><<<mm_grid, 256, 0, stream>>>(
        T1, T2, Wb3, biasp + 256, T3, stats + 512, n);

    // ---- mlp1 layer1
    fold_w<<<96, 64, 0, stream>>>(m1w, m1b, stats + 512, l1g, l1bt, 96,
                                  nullptr, nullptr, nullptr, 0, Wb4, biasp + 384, 96, inv_n);
    mm_mfma<96, 0, 96, 96><<<mm_grid, 256, 0, stream>>>(
        T3, nullptr, Wb4, biasp + 384, T4, stats + 768, n);

    // ---- mlp1 layer2 (DOUT=8 pad 16)
    fold_w<<<16, 64, 0, stream>>>(m2w, m2b, stats + 768, m1g, m1bt, 96,
                                  nullptr, nullptr, nullptr, 0, Wb5, biasp + 512, 8, inv_n);
    mm_mfma<96, 0, 16, 8><<<mm_grid, 256, 0, stream>>>(
        T4, nullptr, Wb5, biasp + 512, T5, stats + 1024, n);

    // ---- final BN -> d_out
    bn_apply_out<<<(n * 8 + 255) / 256, 256, 0, stream>>>(T5, stats + 1024, m2g, m2bt,
                                                          (float*)d_out, n * 8, inv_n);
}

// Round 14
// 333.605 us; speedup vs baseline: 1.1594x; 1.1594x over previous
//
#include <hip/hip_runtime.h>

// ---------------------------------------------------------------------------
// GINENet, N=50000, E=800000, D=128.
// Round 30: revert r29 (fused-scan spin hand-off cost +47us: 195 blocks
// spinning on one cacheline starve block 0; agg (256,8) neutral -> agg is
// VMEM-latency-bound, frozen). Back to r28 exactly (338.7us measured best):
// separate bkt_scan, agg (256,4), 1024-thread scatter SC_CHUNK=4096.
// Only change: stats|bcnt|bfill contiguous -> ONE memset instead of two.
// ---------------------------------------------------------------------------

typedef unsigned short u16;
typedef unsigned int u32;

using bfrag = __attribute__((ext_vector_type(8))) short;  // 8 bf16
using ffrag = __attribute__((ext_vector_type(4))) float;  // 4 fp32 acc

__device__ __forceinline__ u16 f2b(float f) {
    u32 u = __float_as_uint(f);
    return (u16)((u + 0x7FFFu + ((u >> 16) & 1u)) >> 16);   // RNE
}
__device__ __forceinline__ float b2f(u16 h) {
    return __uint_as_float(((u32)h) << 16);
}
__device__ __forceinline__ float b2f_lo(u32 g) { return __uint_as_float(g << 16); }
__device__ __forceinline__ float b2f_hi(u32 g) { return __uint_as_float(g & 0xffff0000u); }

#define BN_EPS 1e-5f
#define BKT_SHIFT 6
#define BKT_NODES 64
#define NBKT_MAX 1024
#define SC_CHUNK 4096
#define SC_THREADS 1024
#define HCHUNK 8192

// ============ weight fold (+BN from raw stats) -> FRAGMENT-MAJOR ============
__device__ __forceinline__
void fold_row(const float* __restrict__ W, const float* __restrict__ bias,
              const float* __restrict__ stA, const float* __restrict__ gA,
              const float* __restrict__ btA, int DA,
              const float* __restrict__ stB, const float* __restrict__ gB,
              const float* __restrict__ btB, int DB,
              u16* __restrict__ WbSw, float* __restrict__ biasp,
              int DOUT, float inv_n, int o, int lane) {
    int DIN = DA + DB;
    int NKT = DIN >> 5;
    int cf = o >> 4, mrow = o & 15;
    if (o >= DOUT) {                    // pad row: zeros
        for (int k = lane; k < DIN; k += 64) {
            int kt = k >> 5, kg = (k >> 3) & 3, e = k & 7;
            WbSw[(((cf * NKT + kt) << 6) + (kg << 4) + mrow) * 8 + e] = 0;
        }
        if (lane == 0) biasp[o] = 0.f;
        return;
    }
    float part = 0.f;
    for (int k = lane; k < DIN; k += 64) {
        float w = W[o * DIN + k];
        float sc = 1.f, sh = 0.f;
        if (k < DA) {
            if (stA) {
                float mu = stA[k] * inv_n;
                float var = stA[DA + k] * inv_n - mu * mu;
                sc = gA[k] * rsqrtf(var + BN_EPS);
                sh = fmaf(-mu, sc, btA[k]);
            }
        } else {
            int kb = k - DA;
            if (stB) {
                float mu = stB[kb] * inv_n;
                float var = stB[DB + kb] * inv_n - mu * mu;
                sc = gB[kb] * rsqrtf(var + BN_EPS);
                sh = fmaf(-mu, sc, btB[kb]);
            }
        }
        int kt = k >> 5, kg = (k >> 3) & 3, e = k & 7;
        WbSw[(((cf * NKT + kt) << 6) + (kg << 4) + mrow) * 8 + e] = f2b(w * sc);
        part += w * sh;
    }
    for (int off = 32; off; off >>= 1) part += __shfl_down(part, off);
    if (lane == 0) biasp[o] = bias[o] + part;
}

__global__ __launch_bounds__(64)
void fold_w(const float* __restrict__ W, const float* __restrict__ bias,
            const float* __restrict__ stA, const float* __restrict__ gA,
            const float* __restrict__ btA, int DA,
            const float* __restrict__ stB, const float* __restrict__ gB,
            const float* __restrict__ btB, int DB,
            u16* __restrict__ WbSw, float* __restrict__ biasp, int DOUT, float inv_n) {
    fold_row(W, bias, stA, gA, btA, DA, stB, gB, btB, DB, WbSw, biasp, DOUT,
             inv_n, blockIdx.x, threadIdx.x);
}

// ===== fused init: bucket histogram + x->bf16 conversion + static folds =====
// Blocks [0, nh):       bucket histogram (LDS-aggregated, ~780 atomics/blk)
// Blocks [nh, nh+48):   identity folds of conv1/conv2 (4 rows/block)
// Block  nh+48:         zero srcEa predication pad
// Blocks [nh+49, ...):  x -> bf16 conversion
__global__ __launch_bounds__(256)
void conv_fold_histo(const int* __restrict__ ei, int E, int nh, int nbkt,
                     const float4* __restrict__ src, uint2* __restrict__ dst, int n4,
                     const float* __restrict__ w1, const float* __restrict__ b1,
                     const float* __restrict__ w2, const float* __restrict__ b2,
                     u16* __restrict__ Wb1, u16* __restrict__ Wb2,
                     float* __restrict__ biasp, int2* __restrict__ padEa,
                     int* __restrict__ bcnt) {
    __shared__ int histL[NBKT_MAX];
    int bx = blockIdx.x;
    const int tid = threadIdx.x;
    if (bx < nh) {
        for (int i = tid; i < nbkt; i += 256) histL[i] = 0;
        __syncthreads();
        int j0 = bx * HCHUNK, j1 = min(E, j0 + HCHUNK);
        for (int j = j0 + tid; j < j1; j += 256)
            atomicAdd(&histL[ei[E + j] >> BKT_SHIFT], 1);
        __syncthreads();
        for (int i = tid; i < nbkt; i += 256) {
            int c = histL[i];
            if (c) atomicAdd(&bcnt[i], c);
        }
        return;
    }
    bx -= nh;
    if (bx < 48) {
        int o = bx * 4 + (tid >> 6);
        int lane = tid & 63;
        if (o < 128)
            fold_row(w1, b1, nullptr, nullptr, nullptr, 128, nullptr, nullptr, nullptr, 0,
                     Wb1, biasp + 0, 128, 0.f, o, lane);
        else if (o < 192)
            fold_row(w2, b2, nullptr, nullptr, nullptr, 128, nullptr, nullptr, nullptr, 0,
                     Wb2, biasp + 128, 64, 0.f, o - 128, lane);
        return;
    }
    if (bx == 48) {
        if (tid < 64) padEa[E + tid] = make_int2(0, 0);
        return;
    }
    int i = (bx - 49) * 256 + tid;
    if (i < n4) {
        float4 v = src[i];
        uint2 o;
        o.x = (u32)f2b(v.x) | ((u32)f2b(v.y) << 16);
        o.y = (u32)f2b(v.z) | ((u32)f2b(v.w) << 16);
        dst[i] = o;
    }
}

// ====== single-block exclusive scan of bucket counts (nbkt <= 1024) ========
__global__ __launch_bounds__(256)
void bkt_scan(const int* __restrict__ bcnt, int* __restrict__ bstart, int nbkt) {
    __shared__ int s[256];
    int t = threadIdx.x;
    int base = t * 4;
    int v0 = (base + 0 < nbkt) ? bcnt[base + 0] : 0;
    int v1 = (base + 1 < nbkt) ? bcnt[base + 1] : 0;
    int v2 = (base + 2 < nbkt) ? bcnt[base + 2] : 0;
    int v3 = (base + 3 < nbkt) ? bcnt[base + 3] : 0;
    int tsum = v0 + v1 + v2 + v3;
    s[t] = tsum;
    __syncthreads();
    for (int off = 1; off < 256; off <<= 1) {
        int x = (t >= off) ? s[t - off] : 0;
        __syncthreads();
        s[t] += x;
        __syncthreads();
    }
    int tbase = s[t] - tsum;
    if (base + 0 < nbkt) bstart[base + 0] = tbase;
    if (base + 1 < nbkt) bstart[base + 1] = tbase + v0;
    if (base + 2 < nbkt) bstart[base + 2] = tbase + v0 + v1;
    if (base + 3 < nbkt) bstart[base + 3] = tbase + v0 + v1 + v2;
    if (t == 255) bstart[nbkt] = s[255];
}

// Two-level bucketed scatter (block-aggregated atomics), 1024-thread blocks.
__global__ __launch_bounds__(SC_THREADS)
void scatter_bkt2(const int* __restrict__ ei, const float* __restrict__ ea,
                  const int* __restrict__ bstart, int* __restrict__ bfill,
                  int2* __restrict__ bedges, int E, int nbkt) {
    __shared__ int cntL[NBKT_MAX];
    __shared__ int baseL[NBKT_MAX];
    const int tid = threadIdx.x;
    const int e0 = blockIdx.x * SC_CHUNK;
    const int e1 = min(E, e0 + SC_CHUNK);
    for (int i = tid; i < nbkt; i += SC_THREADS) cntL[i] = 0;
    __syncthreads();
    for (int j = e0 + tid; j < e1; j += SC_THREADS)
        atomicAdd(&cntL[ei[E + j] >> BKT_SHIFT], 1);
    __syncthreads();
    for (int i = tid; i < nbkt; i += SC_THREADS) {
        int c = cntL[i];
        baseL[i] = c ? (bstart[i] + atomicAdd(&bfill[i], c)) : 0;
        cntL[i] = 0;   // reuse as cursor
    }
    __syncthreads();
    for (int j = e0 + tid; j < e1; j += SC_THREADS) {
        int src = ei[j];
        int dst = ei[E + j];
        int b = dst >> BKT_SHIFT;
        int pos = baseL[b] + atomicAdd(&cntL[b], 1);
        bedges[pos] = make_int2(src | ((dst & (BKT_NODES - 1)) << 20),
                                __float_as_int(ea[j]));
    }
}

// Bucket-local compaction + per-node CSR metadata.
// Counts the bucket's 64 node-bins in LDS, wave64-scans them, writes
// startA/cnt for its nodes, then reorders edges to exact CSR order.
__global__ __launch_bounds__(256)
void compact_bkt(const int2* __restrict__ bedges, const int* __restrict__ bstart,
                 int2* __restrict__ srcEa, int* __restrict__ startA,
                 int* __restrict__ cnt, int n) {
    __shared__ int cntL[BKT_NODES];
    __shared__ int baseS[BKT_NODES];
    __shared__ int fillL[BKT_NODES];
    const int b = blockIdx.x;
    const int v0 = b << BKT_SHIFT;
    const int e0 = bstart[b];
    const int e1 = bstart[b + 1];
    const int tid = threadIdx.x;
    if (tid < BKT_NODES) { cntL[tid] = 0; fillL[tid] = 0; }
    __syncthreads();
    for (int j = e0 + tid; j < e1; j += 256)
        atomicAdd(&cntL[(bedges[j].x >> 20) & (BKT_NODES - 1)], 1);
    __syncthreads();
    if (tid < 64) {
        int c = cntL[tid];
        int s = c;                       // inclusive scan over the wave
#pragma unroll
        for (int d = 1; d < 64; d <<= 1) {
            int y = __shfl_up(s, d);
            if (tid >= d) s += y;
        }
        int gstart = e0 + s - c;         // exclusive
        baseS[tid] = gstart;
        int v = v0 + tid;
        if (v < n) { startA[v] = gstart; cnt[v] = c; }
    }
    __syncthreads();
    for (int j = e0 + tid; j < e1; j += 256) {
        int2 p = bedges[j];
        int dl = (p.x >> 20) & (BKT_NODES - 1);
        int pos = baseS[dl] + atomicAdd(&fillL[dl], 1);
        srcEa[pos] = make_int2(p.x & 0xFFFFF, p.y);
    }
}

// =================== gather-side GINE aggregation ===========================
// r23 structure (measured best): uniform values scalar via readfirstlane,
// predicated rounds of 8, 1-deep edge-record prefetch. bs = b + sh folded.
// agg is VMEM-latency-bound at ~37us (r24/r29 probes both neutral) -- frozen.
template <bool BN>
__global__ __launch_bounds__(256, 4)
void agg_csr(const u32* __restrict__ x2, const float* __restrict__ ew,
             const float* __restrict__ eb, const int2* __restrict__ srcEa,
             const int* __restrict__ start, const int* __restrict__ cnt,
             const float* __restrict__ stats, const float* __restrict__ g,
             const float* __restrict__ bt, u32* __restrict__ agg2, int n, float inv_n) {
    int v = blockIdx.x * 4 + (threadIdx.x >> 6);
    if (v >= n) return;
    const int lane = threadIdx.x & 63;
    const int s0 = __builtin_amdgcn_readfirstlane(start[v]);
    const int deg = __builtin_amdgcn_readfirstlane(cnt[v]);

    // hoisted independent loads
    u32 gs = x2[(u32)v * 64u + (u32)lane];
    int2 p[8], pn[8];
#pragma unroll
    for (int t = 0; t < 8; ++t) p[t] = srcEa[s0 + t];   // pad makes this safe

    float w0 = ew[2 * lane], w1 = ew[2 * lane + 1];
    float b0 = eb[2 * lane], b1 = eb[2 * lane + 1];
    float sc0 = 1.f, sh0 = 0.f, sc1 = 1.f, sh1 = 0.f;
    if (BN) {
        float mu0 = stats[2 * lane] * inv_n;
        float va0 = stats[128 + 2 * lane] * inv_n - mu0 * mu0;
        sc0 = g[2 * lane] * rsqrtf(va0 + BN_EPS);
        sh0 = fmaf(-mu0, sc0, bt[2 * lane]);
        float mu1 = stats[2 * lane + 1] * inv_n;
        float va1 = stats[129 + 2 * lane] * inv_n - mu1 * mu1;
        sc1 = g[2 * lane + 1] * rsqrtf(va1 + BN_EPS);
        sh1 = fmaf(-mu1, sc1, bt[2 * lane + 1]);
    }
    const float bs0 = BN ? (b0 + sh0) : b0;   // fold BN shift into edge bias
    const float bs1 = BN ? (b1 + sh1) : b1;

    float a0 = 0.f, a1 = 0.f;
    for (int j = 0; j < deg; j += 8) {
        // issue this round's row gathers (saddr form: uniform row base + lane)
        u32 gg[8];
#pragma unroll
        for (int t = 0; t < 8; ++t) {
            u32 row = (u32)__builtin_amdgcn_readfirstlane(p[t].x);
            gg[t] = x2[row * 64u + (u32)lane];
        }
        // prefetch next round's edge records (s_load, overlaps gathers)
        if (j + 8 < deg) {
#pragma unroll
            for (int t = 0; t < 8; ++t) pn[t] = srcEa[s0 + j + 8 + t];
        }
#pragma unroll
        for (int t = 0; t < 8; ++t) {
            float mf = (j + t < deg) ? 1.f : 0.f;       // uniform -> s_cselect
            float eav = __int_as_float(p[t].y);
            float t0 = fmaf(eav, w0, bs0);
            float t1 = fmaf(eav, w1, bs1);
            float m0 = BN ? fmaxf(fmaf(b2f_lo(gg[t]), sc0, t0), 0.f)
                          : fmaxf(b2f_lo(gg[t]) + t0, 0.f);
            float m1 = BN ? fmaxf(fmaf(b2f_hi(gg[t]), sc1, t1), 0.f)
                          : fmaxf(b2f_hi(gg[t]) + t1, 0.f);
            a0 = fmaf(m0, mf, a0);
            a1 = fmaf(m1, mf, a1);
        }
#pragma unroll
        for (int t = 0; t < 8; ++t) p[t] = pn[t];
    }

    float r0 = (BN ? fmaf(b2f_lo(gs), sc0, sh0) : b2f_lo(gs)) + a0;
    float r1 = (BN ? fmaf(b2f_hi(gs), sc1, sh1) : b2f_hi(gs)) + a1;
    agg2[(u32)v * 64u + (u32)lane] = (u32)f2b(r0) | ((u32)f2b(r1) << 16);
}

// ======================= MFMA matmul + relu + stats =========================
// r14 form (measured best): zero staging, NH=2/BM=128. A-fragments straight
// from global; B-fragments from fragment-major global W. LDS = stats only.
template <int DIN0, int DIN1, int DOUTP, int DOUT>
__global__ __launch_bounds__(256)
void mm_mfma(const u16* __restrict__ in0, const u16* __restrict__ in1,
             const u16* __restrict__ WbSw, const float* __restrict__ biasp,
             u16* __restrict__ out, float* __restrict__ stats, int n) {
    constexpr int DIN = DIN0 + DIN1;
    constexpr int BM = 128;
    constexpr int NH = 2;
    constexpr int NCF = DOUTP / 16;
    constexpr int NKT = DIN / 32;
    __shared__ float cs[2 * DOUTP];
    const int tid = threadIdx.x;
    const int row0 = blockIdx.x * BM;
    const int wv = tid >> 6;
    const int lane = tid & 63;
    const int mrow = lane & 15;
    const int kg = lane >> 4;

    ffrag acc[NH][NCF];
#pragma unroll
    for (int h = 0; h < NH; ++h)
#pragma unroll
        for (int cf = 0; cf < NCF; ++cf) acc[h][cf] = (ffrag){0.f, 0.f, 0.f, 0.f};

    const int r0w = row0 + wv * 16 + mrow;   // this lane's base row
#pragma unroll
    for (int kt = 0; kt < NKT; ++kt) {
        const int gk = kt * 32 + kg * 8;
        bfrag a[NH];
#pragma unroll
        for (int h = 0; h < NH; ++h) {
            long gr = r0w + h * 64;
            const u16* src = (DIN1 == 0 || gk < DIN0)
                                 ? (in0 + gr * DIN0 + gk)
                                 : (in1 + gr * DIN1 + (gk - DIN0));
            a[h] = *(const bfrag*)src;
        }
#pragma unroll
        for (int cf = 0; cf < NCF; ++cf) {
            bfrag bb = *(const bfrag*)(WbSw + (((long)(cf * NKT + kt) << 6) + lane) * 8);
#pragma unroll
            for (int h = 0; h < NH; ++h)
                acc[h][cf] = __builtin_amdgcn_mfma_f32_16x16x32_bf16(a[h], bb, acc[h][cf], 0, 0, 0);
        }
    }

    // ---- epilogue: bias + relu + bf16 store + column stats
    for (int i = tid; i < 2 * DOUTP; i += 256) cs[i] = 0.f;
    __syncthreads();

    const int col = lane & 15;
#pragma unroll
    for (int cf = 0; cf < NCF; ++cf) {
        int c = cf * 16 + col;
        if (DOUTP != DOUT && c >= DOUT) continue;
        float bv = biasp[c];
        float bsum = 0.f, bss = 0.f;
#pragma unroll
        for (int h = 0; h < NH; ++h) {
#pragma unroll
            for (int r = 0; r < 4; ++r) {
                int gr = row0 + h * 64 + wv * 16 + kg * 4 + r;
                if (gr < n) {
                    float v = fmaxf(acc[h][cf][r] + bv, 0.f);
                    out[(long)gr * DOUT + c] = f2b(v);
                    bsum += v;
                    bss += v * v;
                }
            }
        }
        atomicAdd(&cs[c], bsum);
        atomicAdd(&cs[DOUT + c], bss);
    }
    __syncthreads();
    for (int i = tid; i < 2 * DOUT; i += 256) atomicAdd(&stats[i], cs[i]);
}

// ===================== final BN (raw stats -> output) =======================
__global__ void bn_apply_out(const u16* __restrict__ t, const float* __restrict__ stats,
                             const float* __restrict__ g, const float* __restrict__ beta,
                             float* __restrict__ out, int total, float inv_n) {
    int i = blockIdx.x * blockDim.x + threadIdx.x;
    if (i < total) {
        int c = i & 7;
        float mu = stats[c] * inv_n;
        float var = stats[8 + c] * inv_n - mu * mu;
        float sc = g[c] * rsqrtf(var + BN_EPS);
        out[i] = fmaf(b2f(t[i]) - mu, sc, beta[c]);
    }
}

// ============================ driver ========================================
extern "C" void kernel_launch(void* const* d_in, const int* in_sizes, int n_in,
                              void* d_out, int out_size, void* d_ws, size_t ws_size,
                              hipStream_t stream) {
    const float* x    = (const float*)d_in[0];
    const int*   ei   = (const int*)d_in[1];
    const float* ea   = (const float*)d_in[2];
    const float* elw  = (const float*)d_in[3];
    const float* elb  = (const float*)d_in[4];
    const float* c1w  = (const float*)d_in[5];
    const float* c1b  = (const float*)d_in[6];
    const float* c1g  = (const float*)d_in[7];
    const float* c1bt = (const float*)d_in[8];
    const float* c2w  = (const float*)d_in[9];
    const float* c2b  = (const float*)d_in[10];
    const float* c2g  = (const float*)d_in[11];
    const float* c2bt = (const float*)d_in[12];
    const float* l1w  = (const float*)d_in[13];
    const float* l1b  = (const float*)d_in[14];
    const float* l1g  = (const float*)d_in[15];
    const float* l1bt = (const float*)d_in[16];
    const float* m1w  = (const float*)d_in[17];
    const float* m1b  = (const float*)d_in[18];
    const float* m1g  = (const float*)d_in[19];
    const float* m1bt = (const float*)d_in[20];
    const float* m2w  = (const float*)d_in[21];
    const float* m2b  = (const float*)d_in[22];
    const float* m2g  = (const float*)d_in[23];
    const float* m2bt = (const float*)d_in[24];

    const int n = in_sizes[0] / 128;   // 50000
    const int E = in_sizes[2];         // 800000
    const float inv_n = 1.0f / (float)n;
    const int nbkt = (n + BKT_NODES - 1) / BKT_NODES;
    const size_t np = (size_t)((n + 127) & ~127);   // padded rows for mm tiles

    char* wp = (char*)d_ws;
    auto alloc = [&](size_t bytes) { char* p = wp; wp += (bytes + 31) & ~(size_t)31; return p; };

    // stats | bcnt | bfill contiguous -> single memset
    float* stats  = (float*)alloc(1280 * 4 + NBKT_MAX * 2 * 4);
    int*   bcnt   = (int*)(stats + 1280);
    int*   bfill  = bcnt + NBKT_MAX;
    float* biasp  = (float*)alloc(5 * 128 * 4);
    int*   bstart = (int*)alloc((NBKT_MAX + 1) * 4); // bucket starts (scan out)
    int*   cnt    = (int*)alloc((size_t)n * 4);      // per-node degree (stored)
    int*   startA = (int*)alloc((size_t)n * 4);      // per-node CSR start
    int2*  bedges = (int2*)alloc((size_t)E * 8);
    int2*  srcEa  = (int2*)alloc((size_t)(E + 64) * 8);   // +64 zero pad rows
    u16*   xb     = (u16*)alloc(np * 128 * 2);
    u16*   Ab     = (u16*)alloc(np * 128 * 2);
    u16*   T1     = (u16*)alloc(np * 128 * 2);
    u16*   T2     = (u16*)alloc(np * 64 * 2);
    u16*   T3     = (u16*)alloc(np * 96 * 2);
    u16*   T4     = (u16*)alloc(np * 96 * 2);
    u16*   T5     = (u16*)alloc(np * 8 * 2);
    u16*   Wb1    = (u16*)alloc(128 * 128 * 2);
    u16*   Wb2    = (u16*)alloc(64 * 128 * 2);
    u16*   Wb3    = (u16*)alloc(96 * 192 * 2);
    u16*   Wb4    = (u16*)alloc(96 * 96 * 2);
    u16*   Wb5    = (u16*)alloc(16 * 96 * 2);

    hipMemsetAsync(stats, 0, 1280 * 4 + NBKT_MAX * 2 * 4, stream);

    const int ag_grid = (n + 3) / 4;
    const int mm_grid = (n + 127) / 128;
    const int sc_grid = (E + SC_CHUNK - 1) / SC_CHUNK;
    const int nh = (E + HCHUNK - 1) / HCHUNK;
    const int ncv = (n * 32 + 255) / 256;

    // ---- fused init: bucket histo + folds + pad + x conversion
    conv_fold_histo<<<nh + 49 + ncv, 256, 0, stream>>>(
        ei, E, nh, nbkt, (const float4*)x, (uint2*)xb, n * 32,
        c1w, c1b, c2w, c2b, Wb1, Wb2, biasp, srcEa, bcnt);
    bkt_scan<<<1, 256, 0, stream>>>(bcnt, bstart, nbkt);
    scatter_bkt2<<<sc_grid, SC_THREADS, 0, stream>>>(ei, ea, bstart, bfill, bedges, E, nbkt);
    compact_bkt<<<nbkt, 256, 0, stream>>>(bedges, bstart, srcEa, startA, cnt, n);

    // ---- conv1: agg(x) -> mm1 -> T1 (pre-BN), stats0
    agg_csr<false><<<ag_grid, 256, 0, stream>>>((const u32*)xb, elw, elb, srcEa, startA, cnt,
                                                nullptr, nullptr, nullptr, (u32*)Ab, n, inv_n);
    mm_mfma<128, 0, 128, 128><<<mm_grid, 256, 0, stream>>>(
        Ab, nullptr, Wb1, biasp + 0, T1, stats + 0, n);

    // ---- conv2: agg(BN(T1) inline) -> mm2 -> T2 (pre-BN), stats1
    agg_csr<true><<<ag_grid, 256, 0, stream>>>((const u32*)T1, elw, elb, srcEa, startA, cnt,
                                               stats + 0, c1g, c1bt, (u32*)Ab, n, inv_n);
    mm_mfma<128, 0, 64, 64><<<mm_grid, 256, 0, stream>>>(
        Ab, nullptr, Wb2, biasp + 128, T2, stats + 256, n);

    // ---- lin1: fold W3 from stats0+stats1, mm on raw [T1|T2]
    fold_w<<<96, 64, 0, stream>>>(l1w, l1b, stats + 0, c1g, c1bt, 128,
                                  stats + 256, c2g, c2bt, 64, Wb3, biasp + 256, 96, inv_n);
    mm_mfma<128, 64, 96, 96><<<mm_grid, 256, 0, stream>>>(
        T1, T2, Wb3, biasp + 256, T3, stats + 512, n);

    // ---- mlp1 layer1
    fold_w<<<96, 64, 0, stream>>>(m1w, m1b, stats + 512, l1g, l1bt, 96,
                                  nullptr, nullptr, nullptr, 0, Wb4, biasp + 384, 96, inv_n);
    mm_mfma<96, 0, 96, 96><<<mm_grid, 256, 0, stream>>>(
        T3, nullptr, Wb4, biasp + 384, T4, stats + 768, n);

    // ---- mlp1 layer2 (DOUT=8 pad 16)
    fold_w<<<16, 64, 0, stream>>>(m2w, m2b, stats + 768, m1g, m1bt, 96,
                                  nullptr, nullptr, nullptr, 0, Wb5, biasp + 512, 8, inv_n);
    mm_mfma<96, 0, 16, 8><<<mm_grid, 256, 0, stream>>>(
        T4, nullptr, Wb5, biasp + 512, T5, stats + 1024, n);

    // ---- final BN -> d_out
    bn_apply_out<<<(n * 8 + 255) / 256, 256, 0, stream>>>(T5, stats + 1024, m2g, m2bt,
                                                          (float*)d_out, n * 8, inv_n);
}